// Round 1
// baseline (1370310.742 us; speedup 1.0000x reference)
//
#include <hip/hip_runtime.h>
#include <stdint.h>

typedef _Float16 f16;
typedef f16 f16x2 __attribute__((ext_vector_type(2)));

#define T_LEN 32768
#define HID   512
#define IN_D  1024
#define OUT_D 128
// dwords of W_ode kept in registers per thread (rest -> LDS). Must be mult of 4.
#define NRW   200

__device__ __forceinline__ float dot2f(uint32_t w, uint32_t v, float acc) {
    return __builtin_amdgcn_fdot2(__builtin_bit_cast(f16x2, w),
                                  __builtin_bit_cast(f16x2, v), acc, false);
}

__device__ __forceinline__ float fast_tanh(float z) {
    float e = __expf(2.f * z);
    return 1.f - 2.f * __builtin_amdgcn_rcpf(e + 1.f);
}

// ---------------------------------------------------------------------------
// K0: convert W_ode / W_h (fp32) into f16-packed layouts for the scan kernel.
// thread t owns rows [ (t>>3)*8 , +8 ) x k-cols [ (t&7)*64 , +64 ).
// flat = rl*32 + c8*4 + m  (rl row-local 0..7, c8 col-group 0..7, m pair 0..3)
// ode layout: ode_prep[flat*512 + t]            (coalesced reg/LDS load)
// wh  layout: wh_prep[(flat>>2)*2048 + t*4 + (flat&3)]  (per-lane dwordx4)
// ---------------------------------------------------------------------------
__global__ __launch_bounds__(512) void k_prep(const float* __restrict__ W_ode,
                                              const float* __restrict__ W_h,
                                              uint32_t* __restrict__ ode_prep,
                                              uint32_t* __restrict__ wh_prep) {
    const int t  = threadIdx.x;
    const int rg = t >> 3, kg = t & 7;
    const bool is_wh = (blockIdx.x == 1);
    const float* W = is_wh ? W_h : W_ode;
    for (int f = 0; f < 256; ++f) {
        int rl = f >> 5, c8 = (f >> 2) & 7, m = f & 3;
        int row = rg * 8 + rl;
        int col = kg * 64 + c8 * 8 + m * 2;
        f16x2 p;
        p.x = (f16)W[row * HID + col];
        p.y = (f16)W[row * HID + col + 1];
        uint32_t u = __builtin_bit_cast(uint32_t, p);
        if (is_wh) wh_prep[(f >> 2) * 2048 + t * 4 + (f & 3)] = u;
        else       ode_prep[f * 512 + t] = u;
    }
}

// ---------------------------------------------------------------------------
// K1: pre[i][j] = W_in @ x_i + b_in + b_h   (fp32 tiled GEMM)
// grid 1024: block = (iblk = bid>>1 -> 64 rows of x, jb = bid&1 -> 256 cols)
// ---------------------------------------------------------------------------
__global__ __launch_bounds__(512) void k_pre(const float* __restrict__ x,
                                             const float* __restrict__ W_in,
                                             const float* __restrict__ b_in,
                                             const float* __restrict__ b_h,
                                             float* __restrict__ pre32,
                                             uint16_t* __restrict__ pre16,
                                             int preF32) {
    __shared__ float xs[64][34];
    __shared__ float wsh[256][34];
    const int t  = threadIdx.x;
    const int i0 = (blockIdx.x >> 1) * 64;
    const int j0 = (blockIdx.x & 1) * 256;
    const int ti = t >> 5, tj = t & 31;

    float acc[4][8];
#pragma unroll
    for (int a = 0; a < 4; ++a)
#pragma unroll
        for (int b = 0; b < 8; ++b) acc[a][b] = 0.f;

    for (int kb = 0; kb < 32; ++kb) {
        __syncthreads();
        {   // x tile: 64 x 32
            int r = t >> 3, c = (t & 7) * 4;
            float4 v = *(const float4*)&x[(size_t)(i0 + r) * IN_D + kb * 32 + c];
            xs[r][c] = v.x; xs[r][c + 1] = v.y; xs[r][c + 2] = v.z; xs[r][c + 3] = v.w;
        }
        {   // W tile: 256 x 32
            int jr = t >> 1, c0 = (t & 1) * 16;
#pragma unroll
            for (int q = 0; q < 4; ++q) {
                float4 v = *(const float4*)&W_in[(size_t)(j0 + jr) * IN_D + kb * 32 + c0 + q * 4];
                wsh[jr][c0 + q * 4]     = v.x; wsh[jr][c0 + q * 4 + 1] = v.y;
                wsh[jr][c0 + q * 4 + 2] = v.z; wsh[jr][c0 + q * 4 + 3] = v.w;
            }
        }
        __syncthreads();
#pragma unroll 4
        for (int k = 0; k < 32; ++k) {
            float xv[4], wv[8];
#pragma unroll
            for (int ii = 0; ii < 4; ++ii) xv[ii] = xs[ti * 4 + ii][k];
#pragma unroll
            for (int jj = 0; jj < 8; ++jj) wv[jj] = wsh[tj + 32 * jj][k];
#pragma unroll
            for (int ii = 0; ii < 4; ++ii)
#pragma unroll
                for (int jj = 0; jj < 8; ++jj)
                    acc[ii][jj] = fmaf(xv[ii], wv[jj], acc[ii][jj]);
        }
    }
#pragma unroll
    for (int ii = 0; ii < 4; ++ii)
#pragma unroll
        for (int jj = 0; jj < 8; ++jj) {
            int ig = i0 + ti * 4 + ii, jg = j0 + tj + 32 * jj;
            float r = acc[ii][jj] + b_in[jg] + b_h[jg];
            if (preF32) pre32[(size_t)ig * HID + jg] = r;
            else        pre16[(size_t)ig * HID + jg] = __builtin_bit_cast(uint16_t, (f16)r);
        }
}

// ---------------------------------------------------------------------------
// K2: the sequential scan. One workgroup, 512 threads (8 waves) on one CU.
// thread t: owns W rows [ (t>>3)*8, +8 ) x k [ (t&7)*64, +64 ); after the
// 8-lane shuffle reduce it owns h[t] (fp32, register-resident).
// ---------------------------------------------------------------------------
__global__ __launch_bounds__(512, 2) void k_scan(
    const uint32_t* __restrict__ ode_prep, const uint32_t* __restrict__ wh_prep,
    const float* __restrict__ pre32, const uint16_t* __restrict__ pre16, int preF32,
    const float* __restrict__ tarr, const float* __restrict__ b_ode,
    const float* __restrict__ W_dec, const float* __restrict__ b_dec,
    float* __restrict__ out)
{
    __shared__ uint32_t wlds[28 * 1024];      // 112KB: W_ode tail, [pair][t][2]
    __shared__ uint16_t vbuf[2][576];         // f16 v-vector, 72-elem row stride
    __shared__ float    hbuf[HID];

    const int t  = threadIdx.x;
    const int kg = t & 7;

    uint32_t wreg[NRW];
#pragma unroll
    for (int d = 0; d < NRW; ++d) wreg[d] = ode_prep[d * 512 + t];
#pragma unroll
    for (int d = NRW; d < 256; ++d) {
        int L = d - NRW;
        wlds[(L >> 1) * 1024 + t * 2 + (L & 1)] = ode_prep[d * 512 + t];
    }
    const float bo = b_ode[t];
    __syncthreads();

    int cur = 1;
    auto push_v = [&](float val) {
        int nxt = cur ^ 1;
        vbuf[nxt][(t >> 6) * 72 + (t & 63)] = __builtin_bit_cast(uint16_t, (f16)val);
        __syncthreads();
        cur = nxt;
    };

    auto mv_ode = [&]() -> float {
        float acc[8] = {0.f, 0.f, 0.f, 0.f, 0.f, 0.f, 0.f, 0.f};
        const uint16_t* vb = &vbuf[cur][kg * 72];
#pragma unroll
        for (int c8 = 0; c8 < 8; ++c8) {
            const uint2 q0 = *(const uint2*)(vb + c8 * 8);
            const uint2 q1 = *(const uint2*)(vb + c8 * 8 + 4);
#pragma unroll
            for (int rl = 0; rl < 8; ++rl) {
                const int f0 = rl * 32 + c8 * 4;
                uint32_t w0, w1, w2, w3;
                if (f0 >= NRW) {
                    const int L = f0 - NRW;
                    const uint2 wa = *(const uint2*)&wlds[(L >> 1) * 1024 + t * 2];
                    const uint2 wb = *(const uint2*)&wlds[((L >> 1) + 1) * 1024 + t * 2];
                    w0 = wa.x; w1 = wa.y; w2 = wb.x; w3 = wb.y;
                } else {
                    w0 = wreg[f0]; w1 = wreg[f0 + 1]; w2 = wreg[f0 + 2]; w3 = wreg[f0 + 3];
                }
                acc[rl] = dot2f(w0, q0.x, acc[rl]);
                acc[rl] = dot2f(w1, q0.y, acc[rl]);
                acc[rl] = dot2f(w2, q1.x, acc[rl]);
                acc[rl] = dot2f(w3, q1.y, acc[rl]);
            }
        }
#pragma unroll
        for (int m = 1; m <= 4; m <<= 1)
#pragma unroll
            for (int rl = 0; rl < 8; ++rl) acc[rl] += __shfl_xor(acc[rl], m, 8);
        float z = acc[0];
#pragma unroll
        for (int rl = 1; rl < 8; ++rl) if (kg == rl) z = acc[rl];
        return z;
    };

    auto mv_wh = [&]() -> float {
        float acc[8] = {0.f, 0.f, 0.f, 0.f, 0.f, 0.f, 0.f, 0.f};
        const uint16_t* vb = &vbuf[cur][kg * 72];
        const uint4* wp = (const uint4*)wh_prep;   // uint4 idx = (flat>>2)*512 + t
        uint4 buf[4][2];
#pragma unroll
        for (int pp = 0; pp < 4; ++pp) {           // pieces 0,4,8,12 (rl 0..3, pc 0)
            const int p = pp * 4;
            buf[pp][0] = wp[(2 * p) * 512 + t];
            buf[pp][1] = wp[(2 * p + 1) * 512 + t];
        }
#pragma unroll
        for (int n = 0; n < 32; ++n) {
            const int p  = (n & 7) * 4 + (n >> 3); // rl-interleaved order: 8 acc chains
            const int rl = n & 7;
            const int c8a = (p & 3) * 2, c8b = c8a + 1;
            const uint2 qa0 = *(const uint2*)(vb + c8a * 8);
            const uint2 qa1 = *(const uint2*)(vb + c8a * 8 + 4);
            const uint2 qb0 = *(const uint2*)(vb + c8b * 8);
            const uint2 qb1 = *(const uint2*)(vb + c8b * 8 + 4);
            const uint4 a = buf[n & 3][0];
            const uint4 b = buf[n & 3][1];
            if (n + 4 < 32) {                      // prefetch 4 iterations ahead
                const int np = ((n + 4) & 7) * 4 + ((n + 4) >> 3);
                buf[n & 3][0] = wp[(2 * np) * 512 + t];
                buf[n & 3][1] = wp[(2 * np + 1) * 512 + t];
            }
            acc[rl] = dot2f(a.x, qa0.x, acc[rl]);
            acc[rl] = dot2f(a.y, qa0.y, acc[rl]);
            acc[rl] = dot2f(a.z, qa1.x, acc[rl]);
            acc[rl] = dot2f(a.w, qa1.y, acc[rl]);
            acc[rl] = dot2f(b.x, qb0.x, acc[rl]);
            acc[rl] = dot2f(b.y, qb0.y, acc[rl]);
            acc[rl] = dot2f(b.z, qb1.x, acc[rl]);
            acc[rl] = dot2f(b.w, qb1.y, acc[rl]);
        }
#pragma unroll
        for (int m = 1; m <= 4; m <<= 1)
#pragma unroll
            for (int rl = 0; rl < 8; ++rl) acc[rl] += __shfl_xor(acc[rl], m, 8);
        float z = acc[0];
#pragma unroll
        for (int rl = 1; rl < 8; ++rl) if (kg == rl) z = acc[rl];
        return z;
    };

    // h0 = tanh(pre[0])
    float h;
    {
        float p0 = preF32 ? pre32[t] : (float)__builtin_bit_cast(f16, pre16[t]);
        h = fast_tanh(p0);
    }
    push_v(h);                                    // writes vbuf[0], cur=0
    float tprev = tarr[0];

#pragma unroll 1
    for (int i = 1; i < T_LEN; ++i) {
        float tcur = tarr[i];
        float dtt  = tcur - tprev; tprev = tcur;
        float dt   = 0.25f * dtt;                 // N_SUB = 4
        float hdt  = 0.5f * dt;
        float pre_t = preF32 ? pre32[(size_t)i * HID + t]
                             : (float)__builtin_bit_cast(f16, pre16[(size_t)i * HID + t]);
#pragma unroll 1
        for (int s = 0; s < 4; ++s) {
            float k1 = fast_tanh(mv_ode() + bo);
            push_v(fmaf(hdt, k1, h));
            float k2 = fast_tanh(mv_ode() + bo);
            push_v(fmaf(hdt, k2, h));
            float k3 = fast_tanh(mv_ode() + bo);
            push_v(fmaf(dt, k3, h));
            float k4 = fast_tanh(mv_ode() + bo);
            h = fmaf(dt * (1.f / 6.f), k1 + 2.f * k2 + 2.f * k3 + k4, h);
            push_v(h);                            // v for next substep / W_h matvec
        }
        float zh = mv_wh();
        h = fast_tanh(pre_t + zh);
        push_v(h);                                // v for next step's RK4
    }

    // decode: out = W_dec @ h + b_dec
    hbuf[t] = h;
    __syncthreads();
    if (t < OUT_D) {
        float a = b_dec[t];
#pragma unroll 4
        for (int r4 = 0; r4 < 128; ++r4) {
            float4 w = *(const float4*)&W_dec[t * HID + r4 * 4];
            a = fmaf(w.x, hbuf[r4 * 4],     a);
            a = fmaf(w.y, hbuf[r4 * 4 + 1], a);
            a = fmaf(w.z, hbuf[r4 * 4 + 2], a);
            a = fmaf(w.w, hbuf[r4 * 4 + 3], a);
        }
        out[t] = a;
    }
}

// ---------------------------------------------------------------------------
extern "C" void kernel_launch(void* const* d_in, const int* in_sizes, int n_in,
                              void* d_out, int out_size, void* d_ws, size_t ws_size,
                              hipStream_t stream) {
    const float* tarr  = (const float*)d_in[0];
    const float* x     = (const float*)d_in[1];
    const float* W_in  = (const float*)d_in[2];
    const float* b_in  = (const float*)d_in[3];
    const float* W_h   = (const float*)d_in[4];
    const float* b_h   = (const float*)d_in[5];
    const float* W_ode = (const float*)d_in[6];
    const float* b_ode = (const float*)d_in[7];
    const float* W_dec = (const float*)d_in[8];
    const float* b_dec = (const float*)d_in[9];
    float* out = (float*)d_out;

    uint8_t*  ws       = (uint8_t*)d_ws;
    uint32_t* ode_prep = (uint32_t*)(ws);                  // 512 KB
    uint32_t* wh_prep  = (uint32_t*)(ws + (512u << 10));   // 512 KB
    void*     pre      = (void*)(ws + (1u << 20));         // 64 MB f32 or 32 MB f16

    size_t need32 = (1u << 20) + (size_t)T_LEN * HID * 4 + 4096;
    int preF32 = (ws_size >= need32) ? 1 : 0;

    hipLaunchKernelGGL(k_prep, dim3(2), dim3(512), 0, stream, W_ode, W_h, ode_prep, wh_prep);
    hipLaunchKernelGGL(k_pre,  dim3(1024), dim3(512), 0, stream, x, W_in, b_in, b_h,
                       (float*)pre, (uint16_t*)pre, preF32);
    hipLaunchKernelGGL(k_scan, dim3(1), dim3(512), 0, stream, ode_prep, wh_prep,
                       (const float*)pre, (const uint16_t*)pre, preF32,
                       tarr, b_ode, W_dec, b_dec, out);
}